// Round 1
// baseline (1274.289 us; speedup 1.0000x reference)
//
#include <hip/hip_runtime.h>

#define NN 10000
#define NE 160000
static constexpr int TPB = 256;

// ---------------- sort / CSR build ----------------

__global__ void k_count(const int* __restrict__ ei, int* __restrict__ cnt_row,
                        int* __restrict__ cnt_col) {
  int e = blockIdx.x * TPB + threadIdx.x;
  if (e >= NE) return;
  atomicAdd(&cnt_row[ei[e]], 1);
  atomicAdd(&cnt_col[ei[NE + e]], 1);
}

__global__ void k_scan2(const int* __restrict__ cnt_r, int* __restrict__ off_r, int* __restrict__ cur_r,
                        const int* __restrict__ cnt_c, int* __restrict__ off_c, int* __restrict__ cur_c) {
  const int* cnt = (blockIdx.x == 0) ? cnt_r : cnt_c;
  int* off = (blockIdx.x == 0) ? off_r : off_c;
  int* cur = (blockIdx.x == 0) ? cur_r : cur_c;
  int lane = threadIdx.x;  // 64 threads (one wave)
  int carry = 0;
  for (int base = 0; base < NN; base += 64) {
    int i = base + lane;
    int v = (i < NN) ? cnt[i] : 0;
    int s = v;
    #pragma unroll
    for (int dd = 1; dd < 64; dd <<= 1) {
      int t = __shfl_up(s, dd, 64);
      if (lane >= dd) s += t;
    }
    int excl = carry + s - v;
    if (i < NN) { off[i] = excl; cur[i] = excl; }
    carry += __shfl(s, 63, 64);
  }
  if (lane == 0) off[NN] = carry;
}

__global__ void k_fill_row(const int* __restrict__ ei, int* __restrict__ cur_row,
                           int* __restrict__ eid_row) {
  int e = blockIdx.x * TPB + threadIdx.x;
  if (e >= NE) return;
  int r = ei[e];
  int p = atomicAdd(&cur_row[r], 1);
  eid_row[p] = e;
}

__global__ void k_fill_col(const int* __restrict__ ei, const int* __restrict__ eid_row,
                           int* __restrict__ cur_col, int* __restrict__ slot_col) {
  int s = blockIdx.x * TPB + threadIdx.x;
  if (s >= NE) return;
  int e = eid_row[s];
  int c = ei[NE + e];
  int p = atomicAdd(&cur_col[c], 1);
  slot_col[p] = s;
}

// ---------------- per-layer kernels ----------------

// xp = x@pw^T + pb ; root = xp@rw^T + cb ; B[n,o] = sum_i xp[i]*eb2[i*D+o]
template<int DIN, int D>
__global__ void __launch_bounds__(TPB)
k_nodeprep(const float* __restrict__ x, const float* __restrict__ pw, const float* __restrict__ pb,
           const float* __restrict__ rw, const float* __restrict__ cb, const float* __restrict__ eb2,
           float* __restrict__ xp, float* __restrict__ root, float* __restrict__ Bb) {
  __shared__ float s_pw[D * DIN], s_rw[D * D], s_eb2[D * D], s_pb[D], s_cb[D];
  for (int t = threadIdx.x; t < D * DIN; t += TPB) s_pw[t] = pw[t];
  for (int t = threadIdx.x; t < D * D; t += TPB) { s_rw[t] = rw[t]; s_eb2[t] = eb2[t]; }
  for (int t = threadIdx.x; t < D; t += TPB) { s_pb[t] = pb[t]; s_cb[t] = cb[t]; }
  __syncthreads();
  int n = blockIdx.x * TPB + threadIdx.x;
  if (n >= NN) return;
  float xv[DIN];
  const float4* x4 = (const float4*)(x + (size_t)n * DIN);
  #pragma unroll
  for (int i = 0; i < DIN / 4; i++) {
    float4 v = x4[i];
    xv[4*i+0] = v.x; xv[4*i+1] = v.y; xv[4*i+2] = v.z; xv[4*i+3] = v.w;
  }
  float xpv[D];
  #pragma unroll
  for (int o = 0; o < D; o++) {
    float a = s_pb[o];
    #pragma unroll
    for (int i = 0; i < DIN; i++) a = fmaf(s_pw[o*DIN + i], xv[i], a);
    xpv[o] = a;
    xp[(size_t)n*D + o] = a;
  }
  #pragma unroll
  for (int o = 0; o < D; o++) {
    float a = s_cb[o];
    #pragma unroll
    for (int i = 0; i < D; i++) a = fmaf(s_rw[o*D + i], xpv[i], a);
    root[(size_t)n*D + o] = a;
  }
  #pragma unroll
  for (int o = 0; o < D; o++) {
    float a = 0.f;
    #pragma unroll
    for (int i = 0; i < D; i++) a = fmaf(xpv[i], s_eb2[i*D + o], a);
    Bb[(size_t)n*D + o] = a;
  }
}

// U[nloc, o*128+k] = sum_i xp[n0+nloc, i] * ew2[i*(D*128) + o*128 + k]
// (ew2 viewed as [D, D*128] row-major).  grid: (D*128/TPB, ceil(nch/16))
template<int D>
__global__ void __launch_bounds__(TPB)
k_ugemm(const float* __restrict__ xp, const float* __restrict__ ew2,
        float* __restrict__ U, int n0, int nch) {
  constexpr int COLS = D * 128;
  int c = blockIdx.x * TPB + threadIdx.x;
  int nb = blockIdx.y * 16;
  __shared__ float s_xp[16][D];
  int nload = nch - nb; if (nload > 16) nload = 16;
  for (int t = threadIdx.x; t < 16 * D; t += TPB) {
    int g = t / D, i = t % D;
    s_xp[g][i] = (g < nload) ? xp[(size_t)(n0 + nb + g) * D + i] : 0.f;
  }
  __syncthreads();
  float acc[16];
  #pragma unroll
  for (int g = 0; g < 16; g++) acc[g] = 0.f;
  #pragma unroll
  for (int i = 0; i < D; i++) {
    float t = ew2[(size_t)i * COLS + c];
    #pragma unroll
    for (int g = 0; g < 16; g++) acc[g] = fmaf(s_xp[g][i], t, acc[g]);
  }
  for (int g = 0; g < nload; g++) U[(size_t)(nb + g) * COLS + c] = acc[g];
}

// per sorted edge slot s in [row_off[n0], row_off[n1]):
// h = relu(ew1 @ ea[e] + eb1) (128) ; msg[s,o] = h . U[row-n0, o, :] + B[row,o]
template<int D>
__global__ void __launch_bounds__(TPB, 2)
k_edgemsg(const int* __restrict__ ei, const int* __restrict__ eid_row,
          const int* __restrict__ row_off, const float* __restrict__ ea,
          const float* __restrict__ ew1, const float* __restrict__ eb1,
          const float* __restrict__ U, const float* __restrict__ Bb,
          float* __restrict__ msg, int n0, int n1) {
  __shared__ float s_w1t[8 * 128];  // [i][k] transposed
  __shared__ float s_b1[128];
  for (int t = threadIdx.x; t < 1024; t += TPB) {
    int k = t >> 3, i = t & 7;
    s_w1t[i * 128 + k] = ew1[t];
  }
  for (int t = threadIdx.x; t < 128; t += TPB) s_b1[t] = eb1[t];
  __syncthreads();
  int sbeg = row_off[n0], send = row_off[n1];
  int s = sbeg + blockIdx.x * TPB + threadIdx.x;
  if (s >= send) return;
  int e = eid_row[s];
  int r = ei[e];
  const float4* ea4 = (const float4*)(ea + (size_t)e * 8);
  float4 a0 = ea4[0], a1 = ea4[1];
  float av[8] = {a0.x, a0.y, a0.z, a0.w, a1.x, a1.y, a1.z, a1.w};
  const float4* w1t4 = (const float4*)s_w1t;  // [i][kq] : i*32+kq
  const float4* b14 = (const float4*)s_b1;
  float4 h[32];
  #pragma unroll
  for (int kq = 0; kq < 32; kq++) {
    float4 acc = b14[kq];
    #pragma unroll
    for (int i = 0; i < 8; i++) {
      float4 w = w1t4[i * 32 + kq];
      acc.x = fmaf(av[i], w.x, acc.x);
      acc.y = fmaf(av[i], w.y, acc.y);
      acc.z = fmaf(av[i], w.z, acc.z);
      acc.w = fmaf(av[i], w.w, acc.w);
    }
    acc.x = fmaxf(acc.x, 0.f); acc.y = fmaxf(acc.y, 0.f);
    acc.z = fmaxf(acc.z, 0.f); acc.w = fmaxf(acc.w, 0.f);
    h[kq] = acc;
  }
  const float4* U4 = (const float4*)(U + (size_t)(r - n0) * (D * 128));
  const float* Bp = Bb + (size_t)r * D;
  float* mp = msg + (size_t)s * D;
  for (int o = 0; o < D; o++) {
    float4 acc = {0.f, 0.f, 0.f, 0.f};
    #pragma unroll
    for (int kq = 0; kq < 32; kq++) {
      float4 u = U4[o * 32 + kq];
      acc.x = fmaf(h[kq].x, u.x, acc.x);
      acc.y = fmaf(h[kq].y, u.y, acc.y);
      acc.z = fmaf(h[kq].z, u.z, acc.z);
      acc.w = fmaf(h[kq].w, u.w, acc.w);
    }
    mp[o] = acc.x + acc.y + acc.z + acc.w + Bp[o];
  }
}

// gather aggregation by col-CSR (deterministic), then x = relu(agg/deg + root) + xp
template<int D>
__global__ void __launch_bounds__(TPB)
k_agg(const int* __restrict__ col_off, const int* __restrict__ slot_col,
      const float* __restrict__ msg, const float* __restrict__ root,
      const float* __restrict__ xp, float* __restrict__ xout) {
  constexpr int GP = TPB / D;
  int g = threadIdx.x / D, o = threadIdx.x % D;
  int n = blockIdx.x * GP + g;
  if (n >= NN) return;
  int p0 = col_off[n], p1 = col_off[n + 1];
  float acc = 0.f;
  for (int p = p0; p < p1; p++) {
    int sc = slot_col[p];
    acc += msg[(size_t)sc * D + o];
  }
  float deg = (p1 > p0) ? (float)(p1 - p0) : 1.f;
  float conv = acc / deg + root[(size_t)n * D + o];
  float rl = conv > 0.f ? conv : 0.f;
  xout[(size_t)n * D + o] = rl + xp[(size_t)n * D + o];
}

// final edge MLP: out = relu((x[row]+x[col]) @ mw0^T + mb0) @ mw1^T + mb1
__global__ void __launch_bounds__(TPB)
k_final(const int* __restrict__ ei, const float* __restrict__ x,
        const float* __restrict__ mw0, const float* __restrict__ mb0,
        const float* __restrict__ mw1, const float* __restrict__ mb1,
        float* __restrict__ out) {
  __shared__ float s_w0[256], s_b0[16], s_w1[16], s_b1;
  for (int t = threadIdx.x; t < 256; t += TPB) s_w0[t] = mw0[t];
  if (threadIdx.x < 16) { s_b0[threadIdx.x] = mb0[threadIdx.x]; s_w1[threadIdx.x] = mw1[threadIdx.x]; }
  if (threadIdx.x == 0) s_b1 = mb1[0];
  __syncthreads();
  int e = blockIdx.x * TPB + threadIdx.x;
  if (e >= NE) return;
  int r = ei[e], c = ei[NE + e];
  const float4* xr4 = (const float4*)(x + (size_t)r * 16);
  const float4* xc4 = (const float4*)(x + (size_t)c * 16);
  float er[16];
  #pragma unroll
  for (int q = 0; q < 4; q++) {
    float4 vr = xr4[q], vc = xc4[q];
    er[4*q+0] = vr.x + vc.x; er[4*q+1] = vr.y + vc.y;
    er[4*q+2] = vr.z + vc.z; er[4*q+3] = vr.w + vc.w;
  }
  float o = s_b1;
  #pragma unroll
  for (int j = 0; j < 16; j++) {
    float t = s_b0[j];
    #pragma unroll
    for (int k = 0; k < 16; k++) t = fmaf(er[k], s_w0[j * 16 + k], t);
    t = fmaxf(t, 0.f);
    o = fmaf(t, s_w1[j], o);
  }
  out[e] = o;
}

// ---------------- host side ----------------

struct LayerPtrs {
  const float *pw, *pb, *ew1, *eb1, *ew2, *eb2, *rw, *cb;
};

template<int DIN, int D>
static void run_layer(const float* xin, float* xout, const LayerPtrs& L,
                      const int* ei, const float* ea,
                      const int* row_off, const int* col_off,
                      const int* eid_row, const int* slot_col,
                      float* xp, float* root, float* Bb, float* msg,
                      float* U, size_t uavail, hipStream_t stream) {
  k_nodeprep<DIN, D><<<(NN + TPB - 1) / TPB, TPB, 0, stream>>>(
      xin, L.pw, L.pb, L.rw, L.cb, L.eb2, xp, root, Bb);
  constexpr int COLS = D * 128;
  size_t per_node = sizeof(float) * COLS;
  size_t ch = uavail / per_node;
  int CH = (ch > (size_t)NN) ? NN : (int)ch;
  if (CH < 1) CH = 1;
  for (int n0 = 0; n0 < NN; n0 += CH) {
    int n1 = n0 + CH; if (n1 > NN) n1 = NN;
    int nch = n1 - n0;
    dim3 gb(COLS / TPB, (nch + 15) / 16);
    k_ugemm<D><<<gb, TPB, 0, stream>>>(xp, L.ew2, U, n0, nch);
    k_edgemsg<D><<<(NE + TPB - 1) / TPB, TPB, 0, stream>>>(
        ei, eid_row, row_off, ea, L.ew1, L.eb1, U, Bb, msg, n0, n1);
  }
  k_agg<D><<<(NN * D + TPB - 1) / TPB, TPB, 0, stream>>>(
      col_off, slot_col, msg, root, xp, xout);
}

extern "C" void kernel_launch(void* const* d_in, const int* in_sizes, int n_in,
                              void* d_out, int out_size, void* d_ws, size_t ws_size,
                              hipStream_t stream) {
  (void)in_sizes; (void)n_in; (void)out_size;
  const float* x0 = (const float*)d_in[0];
  const float* ea = (const float*)d_in[1];
  const int* ei = (const int*)d_in[2];
  LayerPtrs L[4];
  for (int l = 0; l < 4; l++) {
    L[l].pw  = (const float*)d_in[3 + 8 * l];
    L[l].pb  = (const float*)d_in[4 + 8 * l];
    L[l].ew1 = (const float*)d_in[5 + 8 * l];
    L[l].eb1 = (const float*)d_in[6 + 8 * l];
    L[l].ew2 = (const float*)d_in[7 + 8 * l];
    L[l].eb2 = (const float*)d_in[8 + 8 * l];
    L[l].rw  = (const float*)d_in[9 + 8 * l];
    L[l].cb  = (const float*)d_in[10 + 8 * l];
  }
  const float* mw0 = (const float*)d_in[35];
  const float* mb0 = (const float*)d_in[36];
  const float* mw1 = (const float*)d_in[37];
  const float* mb1 = (const float*)d_in[38];
  float* out = (float*)d_out;

  char* w = (char*)d_ws;
  size_t off = 0;
  auto alloc = [&](size_t b) -> void* {
    void* p = w + off;
    off = (off + b + 255) & ~(size_t)255;
    return p;
  };
  int* cnt_row  = (int*)alloc(sizeof(int) * NN);
  int* cnt_col  = (int*)alloc(sizeof(int) * NN);
  int* row_off  = (int*)alloc(sizeof(int) * (NN + 1));
  int* col_off  = (int*)alloc(sizeof(int) * (NN + 1));
  int* cur_row  = (int*)alloc(sizeof(int) * NN);
  int* cur_col  = (int*)alloc(sizeof(int) * NN);
  int* eid_row  = (int*)alloc(sizeof(int) * NE);
  int* slot_col = (int*)alloc(sizeof(int) * NE);
  float* xb0  = (float*)alloc(sizeof(float) * NN * 32);
  float* xb1  = (float*)alloc(sizeof(float) * NN * 32);
  float* xp   = (float*)alloc(sizeof(float) * NN * 32);
  float* root = (float*)alloc(sizeof(float) * NN * 32);
  float* Bb   = (float*)alloc(sizeof(float) * NN * 32);
  float* msg  = (float*)alloc(sizeof(float) * NE * 32);
  float* U = (float*)(w + off);
  size_t uavail = (ws_size > off) ? (ws_size - off) : 0;

  hipMemsetAsync(cnt_row, 0, sizeof(int) * NN, stream);
  hipMemsetAsync(cnt_col, 0, sizeof(int) * NN, stream);
  k_count<<<(NE + TPB - 1) / TPB, TPB, 0, stream>>>(ei, cnt_row, cnt_col);
  k_scan2<<<2, 64, 0, stream>>>(cnt_row, row_off, cur_row, cnt_col, col_off, cur_col);
  k_fill_row<<<(NE + TPB - 1) / TPB, TPB, 0, stream>>>(ei, cur_row, eid_row);
  k_fill_col<<<(NE + TPB - 1) / TPB, TPB, 0, stream>>>(ei, eid_row, cur_col, slot_col);

  float* bufs[2] = {xb0, xb1};
  const float* xin = x0;
  for (int l = 0; l < 4; l++) {
    float* xout = bufs[l & 1];
    if (l == 0) {
      run_layer<16, 32>(xin, xout, L[0], ei, ea, row_off, col_off, eid_row, slot_col,
                        xp, root, Bb, msg, U, uavail, stream);
    } else if (l == 1) {
      run_layer<32, 16>(xin, xout, L[1], ei, ea, row_off, col_off, eid_row, slot_col,
                        xp, root, Bb, msg, U, uavail, stream);
    } else if (l == 2) {
      run_layer<16, 16>(xin, xout, L[2], ei, ea, row_off, col_off, eid_row, slot_col,
                        xp, root, Bb, msg, U, uavail, stream);
    } else {
      run_layer<16, 16>(xin, xout, L[3], ei, ea, row_off, col_off, eid_row, slot_col,
                        xp, root, Bb, msg, U, uavail, stream);
    }
    xin = xout;
  }
  k_final<<<(NE + TPB - 1) / TPB, TPB, 0, stream>>>(ei, xin, mw0, mb0, mw1, mb1, out);
}

// Round 2
// 636.890 us; speedup vs baseline: 2.0008x; 2.0008x over previous
//
#include <hip/hip_runtime.h>

#define NN 10000
#define NE 160000
static constexpr int TPB = 256;

// ---------------- sort / CSR build ----------------

__global__ void k_count(const int* __restrict__ ei, int* __restrict__ cnt_row,
                        int* __restrict__ cnt_col) {
  int e = blockIdx.x * TPB + threadIdx.x;
  if (e >= NE) return;
  atomicAdd(&cnt_row[ei[e]], 1);
  atomicAdd(&cnt_col[ei[NE + e]], 1);
}

__global__ void k_scan2(const int* __restrict__ cnt_r, int* __restrict__ off_r, int* __restrict__ cur_r,
                        const int* __restrict__ cnt_c, int* __restrict__ off_c, int* __restrict__ cur_c) {
  const int* cnt = (blockIdx.x == 0) ? cnt_r : cnt_c;
  int* off = (blockIdx.x == 0) ? off_r : off_c;
  int* cur = (blockIdx.x == 0) ? cur_r : cur_c;
  int lane = threadIdx.x;  // 64 threads (one wave)
  int carry = 0;
  for (int base = 0; base < NN; base += 64) {
    int i = base + lane;
    int v = (i < NN) ? cnt[i] : 0;
    int s = v;
    #pragma unroll
    for (int dd = 1; dd < 64; dd <<= 1) {
      int t = __shfl_up(s, dd, 64);
      if (lane >= dd) s += t;
    }
    int excl = carry + s - v;
    if (i < NN) { off[i] = excl; cur[i] = excl; }
    carry += __shfl(s, 63, 64);
  }
  if (lane == 0) off[NN] = carry;
}

__global__ void k_fill_row(const int* __restrict__ ei, int* __restrict__ cur_row,
                           int* __restrict__ eid_row) {
  int e = blockIdx.x * TPB + threadIdx.x;
  if (e >= NE) return;
  int r = ei[e];
  int p = atomicAdd(&cur_row[r], 1);
  eid_row[p] = e;
}

__global__ void k_fill_col(const int* __restrict__ ei, const int* __restrict__ eid_row,
                           int* __restrict__ cur_col, int* __restrict__ slot_col) {
  int s = blockIdx.x * TPB + threadIdx.x;
  if (s >= NE) return;
  int e = eid_row[s];
  int c = ei[NE + e];
  int p = atomicAdd(&cur_col[c], 1);
  slot_col[p] = s;
}

// ---------------- per-layer kernels ----------------

// xp = x@pw^T + pb ; root = xp@rw^T + cb ; B[n,o] = sum_i xp[i]*eb2[i*D+o]
template<int DIN, int D>
__global__ void __launch_bounds__(TPB)
k_nodeprep(const float* __restrict__ x, const float* __restrict__ pw, const float* __restrict__ pb,
           const float* __restrict__ rw, const float* __restrict__ cb, const float* __restrict__ eb2,
           float* __restrict__ xp, float* __restrict__ root, float* __restrict__ Bb) {
  __shared__ float s_pw[D * DIN], s_rw[D * D], s_eb2[D * D], s_pb[D], s_cb[D];
  for (int t = threadIdx.x; t < D * DIN; t += TPB) s_pw[t] = pw[t];
  for (int t = threadIdx.x; t < D * D; t += TPB) { s_rw[t] = rw[t]; s_eb2[t] = eb2[t]; }
  for (int t = threadIdx.x; t < D; t += TPB) { s_pb[t] = pb[t]; s_cb[t] = cb[t]; }
  __syncthreads();
  int n = blockIdx.x * TPB + threadIdx.x;
  if (n >= NN) return;
  float xv[DIN];
  const float4* x4 = (const float4*)(x + (size_t)n * DIN);
  #pragma unroll
  for (int i = 0; i < DIN / 4; i++) {
    float4 v = x4[i];
    xv[4*i+0] = v.x; xv[4*i+1] = v.y; xv[4*i+2] = v.z; xv[4*i+3] = v.w;
  }
  float xpv[D];
  #pragma unroll
  for (int o = 0; o < D; o++) {
    float a = s_pb[o];
    #pragma unroll
    for (int i = 0; i < DIN; i++) a = fmaf(s_pw[o*DIN + i], xv[i], a);
    xpv[o] = a;
    xp[(size_t)n*D + o] = a;
  }
  #pragma unroll
  for (int o = 0; o < D; o++) {
    float a = s_cb[o];
    #pragma unroll
    for (int i = 0; i < D; i++) a = fmaf(s_rw[o*D + i], xpv[i], a);
    root[(size_t)n*D + o] = a;
  }
  #pragma unroll
  for (int o = 0; o < D; o++) {
    float a = 0.f;
    #pragma unroll
    for (int i = 0; i < D; i++) a = fmaf(xpv[i], s_eb2[i*D + o], a);
    Bb[(size_t)n*D + o] = a;
  }
}

// V[i][k*D+o] = ew2[(i*D+o)*128 + k]   (one-time per layer, 512 KB max)
__global__ void k_trans(const float* __restrict__ ew2, float* __restrict__ V, int D) {
  int t = blockIdx.x * TPB + threadIdx.x;
  int COLS = D * 128;
  if (t >= D * COLS) return;
  int i = t / COLS, c = t - i * COLS;
  int k = c / D, o = c - k * D;
  V[t] = ew2[((size_t)(i * D + o)) * 128 + k];
}

// U[nloc, c] = sum_i xp[n0+nloc, i] * V[i*COLS + c], c = k*D+o
template<int D>
__global__ void __launch_bounds__(TPB)
k_ugemm(const float* __restrict__ xp, const float* __restrict__ V,
        float* __restrict__ U, int n0, int nch) {
  constexpr int COLS = D * 128;
  int c = blockIdx.x * TPB + threadIdx.x;
  int nb = blockIdx.y * 16;
  __shared__ float s_xp[16][D];
  int nload = nch - nb; if (nload > 16) nload = 16;
  for (int t = threadIdx.x; t < 16 * D; t += TPB) {
    int g = t / D, i = t % D;
    s_xp[g][i] = (g < nload) ? xp[(size_t)(n0 + nb + g) * D + i] : 0.f;
  }
  __syncthreads();
  float acc[16];
  #pragma unroll
  for (int g = 0; g < 16; g++) acc[g] = 0.f;
  #pragma unroll
  for (int i = 0; i < D; i++) {
    float t = V[(size_t)i * COLS + c];
    #pragma unroll
    for (int g = 0; g < 16; g++) acc[g] = fmaf(s_xp[g][i], t, acc[g]);
  }
  for (int g = 0; g < nload; g++) U[(size_t)(nb + g) * COLS + c] = acc[g];
}

// Each block handles EB consecutive sorted-edge slots; D/4 threads per edge.
// h computed cooperatively into LDS; U layout [nloc][k][o].
template<int D>
__global__ void __launch_bounds__(TPB)
k_edgemsg2(const int* __restrict__ ei, const int* __restrict__ eid_row,
           const int* __restrict__ row_off, const float* __restrict__ ea,
           const float* __restrict__ ew1, const float* __restrict__ eb1,
           const float* __restrict__ U, const float* __restrict__ Bb,
           float* __restrict__ msg, int n0, int n1) {
  constexpr int OQ = D / 4;       // threads per edge
  constexpr int EB = TPB / OQ;    // edges per block
  int sbeg = row_off[n0], send = row_off[n1];
  int sbase = sbeg + blockIdx.x * EB;
  if (sbase >= send) return;
  __shared__ float s_w1t[8 * 128];       // [i][k]
  __shared__ float s_b1[128];
  __shared__ float s_h[EB * 129];        // padded: stride 129 kills bank conflicts
  __shared__ float s_ea[EB * 8];
  __shared__ int s_r[EB];
  int tid = threadIdx.x;
  for (int t = tid; t < 1024; t += TPB) {
    int k = t >> 3, i = t & 7;
    s_w1t[i * 128 + k] = ew1[t];
  }
  for (int t = tid; t < 128; t += TPB) s_b1[t] = eb1[t];
  for (int t = tid; t < EB * 8; t += TPB) {
    int el = t >> 3, i = t & 7;
    int s = sbase + el;
    s_ea[t] = (s < send) ? ea[(size_t)eid_row[s] * 8 + i] : 0.f;
  }
  if (tid < EB) {
    int s = sbase + tid;
    s_r[tid] = (s < send) ? ei[eid_row[s]] : n0;
  }
  __syncthreads();
  // h[el][k] = relu(b1[k] + sum_i ea[el][i]*w1t[i][k])
  for (int t = tid; t < EB * 128; t += TPB) {
    int el = t >> 7, k = t & 127;
    float a = s_b1[k];
    #pragma unroll
    for (int i = 0; i < 8; i++) a = fmaf(s_ea[el * 8 + i], s_w1t[i * 128 + k], a);
    s_h[el * 129 + k] = fmaxf(a, 0.f);
  }
  __syncthreads();
  int el = tid / OQ, oq = tid % OQ;
  int s = sbase + el;
  if (s >= send) return;
  int r = s_r[el];
  const float4* U4 = (const float4*)(U + (size_t)(r - n0) * (D * 128));
  const float* hp = s_h + el * 129;
  float4 acc = {0.f, 0.f, 0.f, 0.f};
  #pragma unroll 8
  for (int k = 0; k < 128; k++) {
    float hk = hp[k];
    float4 u = U4[k * OQ + oq];
    acc.x = fmaf(hk, u.x, acc.x);
    acc.y = fmaf(hk, u.y, acc.y);
    acc.z = fmaf(hk, u.z, acc.z);
    acc.w = fmaf(hk, u.w, acc.w);
  }
  const float4* B4 = (const float4*)(Bb + (size_t)r * D);
  float4 b = B4[oq];
  acc.x += b.x; acc.y += b.y; acc.z += b.z; acc.w += b.w;
  ((float4*)(msg + (size_t)s * D))[oq] = acc;
}

// gather aggregation by col-CSR (deterministic), then x = relu(agg/deg + root) + xp
template<int D>
__global__ void __launch_bounds__(TPB)
k_agg(const int* __restrict__ col_off, const int* __restrict__ slot_col,
      const float* __restrict__ msg, const float* __restrict__ root,
      const float* __restrict__ xp, float* __restrict__ xout) {
  constexpr int GP = TPB / D;
  int g = threadIdx.x / D, o = threadIdx.x % D;
  int n = blockIdx.x * GP + g;
  if (n >= NN) return;
  int p0 = col_off[n], p1 = col_off[n + 1];
  float acc = 0.f;
  for (int p = p0; p < p1; p++) {
    int sc = slot_col[p];
    acc += msg[(size_t)sc * D + o];
  }
  float deg = (p1 > p0) ? (float)(p1 - p0) : 1.f;
  float conv = acc / deg + root[(size_t)n * D + o];
  float rl = conv > 0.f ? conv : 0.f;
  xout[(size_t)n * D + o] = rl + xp[(size_t)n * D + o];
}

// final edge MLP: out = relu((x[row]+x[col]) @ mw0^T + mb0) @ mw1^T + mb1
__global__ void __launch_bounds__(TPB)
k_final(const int* __restrict__ ei, const float* __restrict__ x,
        const float* __restrict__ mw0, const float* __restrict__ mb0,
        const float* __restrict__ mw1, const float* __restrict__ mb1,
        float* __restrict__ out) {
  __shared__ float s_w0[256], s_b0[16], s_w1[16], s_b1;
  for (int t = threadIdx.x; t < 256; t += TPB) s_w0[t] = mw0[t];
  if (threadIdx.x < 16) { s_b0[threadIdx.x] = mb0[threadIdx.x]; s_w1[threadIdx.x] = mw1[threadIdx.x]; }
  if (threadIdx.x == 0) s_b1 = mb1[0];
  __syncthreads();
  int e = blockIdx.x * TPB + threadIdx.x;
  if (e >= NE) return;
  int r = ei[e], c = ei[NE + e];
  const float4* xr4 = (const float4*)(x + (size_t)r * 16);
  const float4* xc4 = (const float4*)(x + (size_t)c * 16);
  float er[16];
  #pragma unroll
  for (int q = 0; q < 4; q++) {
    float4 vr = xr4[q], vc = xc4[q];
    er[4*q+0] = vr.x + vc.x; er[4*q+1] = vr.y + vc.y;
    er[4*q+2] = vr.z + vc.z; er[4*q+3] = vr.w + vc.w;
  }
  float o = s_b1;
  #pragma unroll
  for (int j = 0; j < 16; j++) {
    float t = s_b0[j];
    #pragma unroll
    for (int k = 0; k < 16; k++) t = fmaf(er[k], s_w0[j * 16 + k], t);
    t = fmaxf(t, 0.f);
    o = fmaf(t, s_w1[j], o);
  }
  out[e] = o;
}

// ---------------- host side ----------------

struct LayerPtrs {
  const float *pw, *pb, *ew1, *eb1, *ew2, *eb2, *rw, *cb;
};

template<int DIN, int D>
static void run_layer(const float* xin, float* xout, const LayerPtrs& L,
                      const int* ei, const float* ea,
                      const int* row_off, const int* col_off,
                      const int* eid_row, const int* slot_col,
                      float* xp, float* root, float* Bb, float* msg, float* Vb,
                      float* U, size_t uavail, hipStream_t stream) {
  k_nodeprep<DIN, D><<<(NN + TPB - 1) / TPB, TPB, 0, stream>>>(
      xin, L.pw, L.pb, L.rw, L.cb, L.eb2, xp, root, Bb);
  constexpr int COLS = D * 128;
  k_trans<<<(D * COLS + TPB - 1) / TPB, TPB, 0, stream>>>(L.ew2, Vb, D);
  size_t per_node = sizeof(float) * COLS;
  size_t ch = uavail / per_node;
  int CH = (ch > (size_t)NN) ? NN : (int)ch;
  if (CH < 1) CH = 1;
  constexpr int EB = TPB / (D / 4);
  for (int n0 = 0; n0 < NN; n0 += CH) {
    int n1 = n0 + CH; if (n1 > NN) n1 = NN;
    int nch = n1 - n0;
    dim3 gb(COLS / TPB, (nch + 15) / 16);
    k_ugemm<D><<<gb, TPB, 0, stream>>>(xp, Vb, U, n0, nch);
    k_edgemsg2<D><<<(NE + EB - 1) / EB, TPB, 0, stream>>>(
        ei, eid_row, row_off, ea, L.ew1, L.eb1, U, Bb, msg, n0, n1);
  }
  k_agg<D><<<(NN * D + TPB - 1) / TPB, TPB, 0, stream>>>(
      col_off, slot_col, msg, root, xp, xout);
}

extern "C" void kernel_launch(void* const* d_in, const int* in_sizes, int n_in,
                              void* d_out, int out_size, void* d_ws, size_t ws_size,
                              hipStream_t stream) {
  (void)in_sizes; (void)n_in; (void)out_size;
  const float* x0 = (const float*)d_in[0];
  const float* ea = (const float*)d_in[1];
  const int* ei = (const int*)d_in[2];
  LayerPtrs L[4];
  for (int l = 0; l < 4; l++) {
    L[l].pw  = (const float*)d_in[3 + 8 * l];
    L[l].pb  = (const float*)d_in[4 + 8 * l];
    L[l].ew1 = (const float*)d_in[5 + 8 * l];
    L[l].eb1 = (const float*)d_in[6 + 8 * l];
    L[l].ew2 = (const float*)d_in[7 + 8 * l];
    L[l].eb2 = (const float*)d_in[8 + 8 * l];
    L[l].rw  = (const float*)d_in[9 + 8 * l];
    L[l].cb  = (const float*)d_in[10 + 8 * l];
  }
  const float* mw0 = (const float*)d_in[35];
  const float* mb0 = (const float*)d_in[36];
  const float* mw1 = (const float*)d_in[37];
  const float* mb1 = (const float*)d_in[38];
  float* out = (float*)d_out;

  char* w = (char*)d_ws;
  size_t off = 0;
  auto alloc = [&](size_t b) -> void* {
    void* p = w + off;
    off = (off + b + 255) & ~(size_t)255;
    return p;
  };
  int* cnt_row  = (int*)alloc(sizeof(int) * NN);
  int* cnt_col  = (int*)alloc(sizeof(int) * NN);
  int* row_off  = (int*)alloc(sizeof(int) * (NN + 1));
  int* col_off  = (int*)alloc(sizeof(int) * (NN + 1));
  int* cur_row  = (int*)alloc(sizeof(int) * NN);
  int* cur_col  = (int*)alloc(sizeof(int) * NN);
  int* eid_row  = (int*)alloc(sizeof(int) * NE);
  int* slot_col = (int*)alloc(sizeof(int) * NE);
  float* xb0  = (float*)alloc(sizeof(float) * NN * 32);
  float* xb1  = (float*)alloc(sizeof(float) * NN * 32);
  float* xp   = (float*)alloc(sizeof(float) * NN * 32);
  float* root = (float*)alloc(sizeof(float) * NN * 32);
  float* Bb   = (float*)alloc(sizeof(float) * NN * 32);
  float* msg  = (float*)alloc(sizeof(float) * NE * 32);
  float* Vb   = (float*)alloc(sizeof(float) * 128 * 32 * 32);  // 512 KB max
  float* U = (float*)(w + off);
  size_t uavail = (ws_size > off) ? (ws_size - off) : 0;

  hipMemsetAsync(cnt_row, 0, sizeof(int) * NN, stream);
  hipMemsetAsync(cnt_col, 0, sizeof(int) * NN, stream);
  k_count<<<(NE + TPB - 1) / TPB, TPB, 0, stream>>>(ei, cnt_row, cnt_col);
  k_scan2<<<2, 64, 0, stream>>>(cnt_row, row_off, cur_row, cnt_col, col_off, cur_col);
  k_fill_row<<<(NE + TPB - 1) / TPB, TPB, 0, stream>>>(ei, cur_row, eid_row);
  k_fill_col<<<(NE + TPB - 1) / TPB, TPB, 0, stream>>>(ei, eid_row, cur_col, slot_col);

  float* bufs[2] = {xb0, xb1};
  const float* xin = x0;
  for (int l = 0; l < 4; l++) {
    float* xout = bufs[l & 1];
    if (l == 0) {
      run_layer<16, 32>(xin, xout, L[0], ei, ea, row_off, col_off, eid_row, slot_col,
                        xp, root, Bb, msg, Vb, U, uavail, stream);
    } else if (l == 1) {
      run_layer<32, 16>(xin, xout, L[1], ei, ea, row_off, col_off, eid_row, slot_col,
                        xp, root, Bb, msg, Vb, U, uavail, stream);
    } else if (l == 2) {
      run_layer<16, 16>(xin, xout, L[2], ei, ea, row_off, col_off, eid_row, slot_col,
                        xp, root, Bb, msg, Vb, U, uavail, stream);
    } else {
      run_layer<16, 16>(xin, xout, L[3], ei, ea, row_off, col_off, eid_row, slot_col,
                        xp, root, Bb, msg, Vb, U, uavail, stream);
    }
    xin = xout;
  }
  k_final<<<(NE + TPB - 1) / TPB, TPB, 0, stream>>>(ei, xin, mw0, mb0, mw1, mb1, out);
}